// Round 6
// baseline (234.720 us; speedup 1.0000x reference)
//
#include <hip/hip_runtime.h>
#include <math.h>

#define NTOK 16384
#define DDIM 2048
#define NEXP 64
#define TOKB 32                  // tokens per block
#define HPLANE 262144            // halfs per W split plane
#define SCALE 4096.0f
#define UNSCALE (1.0f / (SCALE * SCALE))

typedef _Float16 half8 __attribute__((ext_vector_type(8)));
typedef float    f32x4 __attribute__((ext_vector_type(4)));

// Pack W fragment-linear fp16 2-plane split. Block b handles expert-row b (coalesced reads).
// Fragment: tile n, kstep ks, lane l: e = n*16+(l&15), k = ks*32+(l>>4)*8+j.
__global__ __launch_bounds__(256) void pack_w(const float* __restrict__ Wt,
                                              const float* __restrict__ Wn,
                                              _Float16* __restrict__ WB) {
    int t  = blockIdx.x * 256 + threadIdx.x;   // 0..32767
    int e  = t >> 8;                           // 0..127 (block-major -> coalesced row reads)
    int k8 = t & 255;
    int k  = k8 * 8;
    const float* src = ((e < NEXP) ? (Wt + (size_t)e * DDIM)
                                   : (Wn + (size_t)(e - NEXP) * DDIM)) + k;
    int n = e >> 4, ei = e & 15, ks = k8 >> 2, q = k8 & 3;
    size_t off = (((size_t)n * 64 + ks) * 64 + (q * 16 + ei)) * 8;
    half8 h0, h1;
#pragma unroll
    for (int j = 0; j < 8; ++j) {
        float v = src[j] * SCALE;
        _Float16 a = (_Float16)v;
        h0[j] = a;
        h1[j] = (_Float16)(v - (float)a);
    }
    *(half8*)(WB + off)          = h0;
    *(half8*)(WB + HPLANE + off) = h1;
}

// Split a float4 pair into fp16 lo/hi half8s (scaled)
#define CVT(lo4, hi4, L, H)                                             \
    {                                                                   \
        float vv[8] = {lo4.x, lo4.y, lo4.z, lo4.w,                      \
                       hi4.x, hi4.y, hi4.z, hi4.w};                     \
        _Pragma("unroll")                                               \
        for (int m = 0; m < 8; ++m) {                                   \
            float s = vv[m] * SCALE;                                    \
            _Float16 a = (_Float16)s;                                   \
            L[m] = a;                                                   \
            H[m] = (_Float16)(s - (float)a);                            \
        }                                                               \
    }

__global__ __launch_bounds__(512, 4) void router_main(const float* __restrict__ x,
                                                      const _Float16* __restrict__ WB,
                                                      const float* __restrict__ noise,
                                                      float* __restrict__ out) {
    // LDS only for the epilogue: pw[kh][e][33] fp32 partials
    __shared__ float pw[4 * 128 * 33];     // 67584 B -> 2 blocks/CU

    const int tid  = threadIdx.x;
    const int lane = tid & 63;
    const int w    = tid >> 6;        // 0..7
    const int eh   = w & 1;           // expert half (4 tiles of 16)
    const int kh   = w >> 1;          // K quarter (512 k = 16 ksteps)
    const int tok0 = blockIdx.x * TOKB;

    f32x4 acc[2][4];
#pragma unroll
    for (int tt = 0; tt < 2; ++tt)
#pragma unroll
        for (int t = 0; t < 4; ++t) acc[tt][t] = (f32x4){0.f, 0.f, 0.f, 0.f};

    // A-fragment source: lane l -> token (l&15), k-offset (l>>4)*8 within kstep
    const float* a0 = x + (size_t)(tok0 + (lane & 15)) * DDIM + kh * 512 + ((lane >> 4) * 8);
    const float* a1 = a0 + (size_t)16 * DDIM;
    // B-fragment source (fragment-linear pack)
    const _Float16* bb = WB + (((size_t)(eh * 4) * 64 + (size_t)kh * 16) * 64 + lane) * 8;

#pragma unroll
    for (int ks = 0; ks < 16; ++ks) {
        const float* ap0 = a0 + ks * 32;
        const float* ap1 = a1 + ks * 32;
        float4 xl0 = *(const float4*)(ap0);
        float4 xh0 = *(const float4*)(ap0 + 4);
        float4 xl1 = *(const float4*)(ap1);
        float4 xh1 = *(const float4*)(ap1 + 4);
        half8 aL0, aH0, aL1, aH1;
        CVT(xl0, xh0, aL0, aH0);
        CVT(xl1, xh1, aL1, aH1);
        const _Float16* bp = bb + (size_t)ks * 512;
#pragma unroll
        for (int t = 0; t < 4; ++t) {
            half8 b0 = *(const half8*)(bp + (size_t)t * 32768);
            half8 b1 = *(const half8*)(bp + (size_t)t * 32768 + HPLANE);
            acc[0][t] = __builtin_amdgcn_mfma_f32_16x16x32_f16(aL0, b0, acc[0][t], 0, 0, 0);
            acc[0][t] = __builtin_amdgcn_mfma_f32_16x16x32_f16(aH0, b0, acc[0][t], 0, 0, 0);
            acc[0][t] = __builtin_amdgcn_mfma_f32_16x16x32_f16(aL0, b1, acc[0][t], 0, 0, 0);
            acc[1][t] = __builtin_amdgcn_mfma_f32_16x16x32_f16(aL1, b0, acc[1][t], 0, 0, 0);
            acc[1][t] = __builtin_amdgcn_mfma_f32_16x16x32_f16(aH1, b0, acc[1][t], 0, 0, 0);
            acc[1][t] = __builtin_amdgcn_mfma_f32_16x16x32_f16(aL1, b1, acc[1][t], 0, 0, 0);
        }
    }

    // ---- epilogue (round-4/5 verified structure) ----
    // partials: pw[kh][e][33]; D layout: row tok = (l>>4)*4 + r, col e-part = l&15
#pragma unroll
    for (int tt = 0; tt < 2; ++tt)
#pragma unroll
        for (int t = 0; t < 4; ++t) {
            int e    = eh * 64 + t * 16 + (lane & 15);
            int tokl = tt * 16 + ((lane >> 4) << 2);
            int base = (kh * 128 + e) * 33 + tokl;
#pragma unroll
            for (int r = 0; r < 4; ++r)
                pw[base + r] = acc[tt][t][r] * UNSCALE;
        }
    __syncthreads();

    // reduce over kh: thread -> (e = tid>>2, 8 tokens)
    {
        int e  = tid >> 2;
        int t0 = (tid & 3) * 8;
#pragma unroll
        for (int j = 0; j < 8; ++j) {
            int tk = t0 + j;
            float s = pw[(0 * 128 + e) * 33 + tk] + pw[(1 * 128 + e) * 33 + tk]
                    + pw[(2 * 128 + e) * 33 + tk] + pw[(3 * 128 + e) * 33 + tk];
            pw[e * 33 + tk] = s;      // lf[e][tok] in kh0 region (unique owner)
        }
    }
    __syncthreads();

    float4* pt  = (float4*)(pw + 4224);          // [16][32] partial top2
    float4* fin = (float4*)(pw + 4224 + 2048);   // [32] per-token final

    // partial top-2: tok = tid&31, eg = tid>>5 covers 4 experts (ascending)
    {
        const int ptok = tid & 31;
        const int eg   = tid >> 5;
        float v1 = -INFINITY, v2 = -INFINITY;
        int i1 = 0, i2 = 0;
        float4 nz = *(const float4*)(noise + (size_t)(tok0 + ptok) * NEXP + eg * 4);
        float nzv[4] = {nz.x, nz.y, nz.z, nz.w};
#pragma unroll
        for (int cc = 0; cc < 4; ++cc) {
            int e = eg * 4 + cc;
            float lg = pw[e * 33 + ptok];
            float nl = pw[(NEXP + e) * 33 + ptok];
            float soft = log1pf(expf(fminf(nl, 20.f)));
            float cmb  = ((nl > 20.f) ? nl : soft) * nzv[cc] + lg;
            if (cmb > v1)      { v2 = v1; i2 = i1; v1 = cmb; i1 = e; }
            else if (cmb > v2) { v2 = cmb; i2 = e; }
        }
        pt[eg * 32 + ptok] = make_float4(v1, (float)i1, v2, (float)i2);
    }
    __syncthreads();

    // merge 16 partials (ascending keeps jax tie-break: lowest index wins)
    if (tid < 32) {
        float4 g = pt[tid];
        float v1 = g.x, v2 = g.z;
        int i1 = (int)g.y, i2 = (int)g.w;
#pragma unroll
        for (int gg = 1; gg < 16; ++gg) {
            float4 p = pt[gg * 32 + tid];
            if (p.x > v1)      { v2 = v1; i2 = i1; v1 = p.x; i1 = (int)p.y; }
            else if (p.x > v2) { v2 = p.x; i2 = (int)p.y; }
            if (p.z > v1)      { v2 = v1; i2 = i1; v1 = p.z; i1 = (int)p.w; }
            else if (p.z > v2) { v2 = p.z; i2 = (int)p.w; }
        }
        float e2  = expf(v2 - v1);
        float inv = 1.f / (1.f + e2);
        fin[tid] = make_float4((float)i1, (float)i2, inv, e2 * inv);
    }
    __syncthreads();

    // probs: thread -> (tok = tid>>4, 4-expert segment tid&15)
    {
        const int tok = tid >> 4;
        const int sg  = tid & 15;
        float4 f = fin[tok];
        int i1 = (int)f.x, i2 = (int)f.y;
        float o[4];
#pragma unroll
        for (int cc = 0; cc < 4; ++cc) {
            int e = sg * 4 + cc;
            o[cc] = (e == i1) ? f.z : ((e == i2) ? f.w : 0.f);
        }
        *(float4*)(out + (size_t)(tok0 + tok) * NEXP + sg * 4) =
            make_float4(o[0], o[1], o[2], o[3]);
    }
    // indices (as float) after the probs region
    if (tid < 32) {
        float4 f = fin[tid];
        *(float2*)(out + (size_t)NTOK * NEXP + (size_t)(tok0 + tid) * 2) = make_float2(f.x, f.y);
    }
}

extern "C" void kernel_launch(void* const* d_in, const int* in_sizes, int n_in,
                              void* d_out, int out_size, void* d_ws, size_t ws_size,
                              hipStream_t stream) {
    const float* x  = (const float*)d_in[0];
    const float* Wt = (const float*)d_in[1];
    const float* Wn = (const float*)d_in[2];
    const float* nz = (const float*)d_in[3];
    float* out = (float*)d_out;
    _Float16* WB = (_Float16*)d_ws;   // 2 * 262144 halfs = 1 MB scratch

    hipLaunchKernelGGL(pack_w, dim3(128), dim3(256), 0, stream, Wt, Wn, WB);
    hipLaunchKernelGGL(router_main, dim3(NTOK / TOKB), dim3(512), 0, stream, x, WB, nz, out);
}